// Round 6
// baseline (741.987 us; speedup 1.0000x reference)
//
#include <hip/hip_runtime.h>
#include <hip/hip_bf16.h>

#define LDIM 4096
#define FDIM 64
#define KQLEN 1024          // k-range per gemm block (quarter)
#define BROWS 16            // adj rows per gemm block
#define SAP2 1032           // sA row stride in bf16 elems (1024 + 8 pad)
#define PQ_F4 524288        // floats4 per partial quarter: 8*4096*64/4

typedef __attribute__((ext_vector_type(8))) __bf16 bf16x8;
typedef __attribute__((ext_vector_type(4))) float f32x4;

__device__ __forceinline__ unsigned short f2bf(float f) {
    unsigned int u = __float_as_uint(f);
    u += 0x7fffu + ((u >> 16) & 1u);       // round-to-nearest-even
    return (unsigned short)(u >> 16);
}

// Kernel 1: hiddenT[b][o][l] = sum_f text[b][l][f] * weight[f][o], stored bf16 (bits).
// hT[b] = 512 KB -> L2-resident on the batch's XCD; kernel 2 reads B-frags from it.
__global__ __launch_bounds__(256) void hidden_kernel(
    const float* __restrict__ text, const float* __restrict__ weight,
    unsigned short* __restrict__ hT)
{
    const int b  = blockIdx.x & 7;
    const int lc = blockIdx.x >> 3;        // 0..63
    const int l0 = lc * 64;
    __shared__ float sw[64 * 64];          // weight [f][o]
    __shared__ float st[64 * 65];          // text tile [l][f], +1 pad
    const int t = threadIdx.x;
    #pragma unroll
    for (int i = 0; i < 16; ++i) sw[t + i * 256] = weight[t + i * 256];
    const float* tp = text + ((size_t)b * LDIM + l0) * FDIM;
    #pragma unroll
    for (int i = 0; i < 16; ++i) {
        int idx = t + i * 256;
        st[(idx >> 6) * 65 + (idx & 63)] = tp[idx];
    }
    __syncthreads();
    const int l  = t & 63;                 // lane = l -> coalesced bf16 row writes
    const int o0 = (t >> 6) * 16;
    float acc[16];
    #pragma unroll
    for (int i = 0; i < 16; ++i) acc[i] = 0.f;
    for (int f = 0; f < 64; ++f) {
        float tv = st[l * 65 + f];
        #pragma unroll
        for (int i = 0; i < 16; ++i) acc[i] += tv * sw[f * 64 + o0 + i];
    }
    unsigned short* hp = hT + ((size_t)b * FDIM + o0) * LDIM + l0 + l;
    #pragma unroll
    for (int i = 0; i < 16; ++i) hp[(size_t)i * LDIM] = f2bf(acc[i]);
}

// Kernel 2: split-K partial gemm. Block (b, kq, mb) computes
//   partial[kq][b][m0..m0+15][0..63] = adj[b][m0..m0+15][kq*1024 ..+1024) @ hT[b][:][same k]
// adj read per block = 16 rows x 4 KB CONTIGUOUS per row (vs 1 KB chunks before) --
// this is the granule-size experiment. B-fragments come straight from L2 (hT).
__global__ __launch_bounds__(256) void gemm_kernel(
    const float* __restrict__ adj, const unsigned short* __restrict__ hT,
    float* __restrict__ part)
{
    const int b  = blockIdx.x & 7;         // batch -> XCD affinity (hT[b] L2-resident)
    const int kq = (blockIdx.x >> 3) & 3;  // k-quarter (fastest -> built-in k stagger)
    const int mb = blockIdx.x >> 5;        // 0..255 row-tile
    const int m0 = mb * BROWS;
    const int k0 = kq * KQLEN;
    const int tid  = threadIdx.x;
    const int w    = tid >> 6;
    const int lane = tid & 63;
    const int fm = lane & 15;
    const int fq = lane >> 4;

    __shared__ __align__(16) unsigned short sA[BROWS * SAP2];   // A[m][k] bf16, 33 KB

    const float* abase = adj + ((size_t)b * LDIM + m0) * LDIM + k0;

    // Load 16 rows x 1024 f32 = 4096 float4. idx = i*256+tid: row = idx>>8 (= i),
    // col4 = idx&255. Per instruction slot i the whole BLOCK reads row i's full
    // 4 KB contiguously (each wave a 1 KB span of it, 4 waves adjacent).
    float4 aReg[16];
    #pragma unroll
    for (int i = 0; i < 16; ++i) {
        int idx = i * 256 + tid;
        aReg[i] = *(const float4*)(abase + (size_t)(idx >> 8) * LDIM + (idx & 255) * 4);
    }
    #pragma unroll
    for (int i = 0; i < 16; ++i) {
        int idx = i * 256 + tid;
        union { unsigned short us[4]; uint2 v; } pk;
        pk.us[0] = f2bf(aReg[i].x); pk.us[1] = f2bf(aReg[i].y);
        pk.us[2] = f2bf(aReg[i].z); pk.us[3] = f2bf(aReg[i].w);
        *(uint2*)&sA[(idx >> 8) * SAP2 + (idx & 255) * 4] = pk.v;
    }
    __syncthreads();

    // Wave w owns output cols [w*16, w*16+16). B-frags from global hT (L2 hit),
    // double-buffered in groups of 8 kf-steps.
    const unsigned short* hrow = hT + (size_t)b * FDIM * LDIM
                               + (size_t)(w * 16 + fm) * LDIM + k0 + fq * 8;
    bf16x8 bReg[2][8];
    #pragma unroll
    for (int j = 0; j < 8; ++j)
        bReg[0][j] = *(const bf16x8*)(hrow + j * 32);

    f32x4 acc = (f32x4){0.f, 0.f, 0.f, 0.f};
    #pragma unroll
    for (int g = 0; g < 4; ++g) {
        const int cur = g & 1, nxt = cur ^ 1;
        if (g < 3) {
            #pragma unroll
            for (int j = 0; j < 8; ++j)
                bReg[nxt][j] = *(const bf16x8*)(hrow + ((g + 1) * 8 + j) * 32);
        }
        #pragma unroll
        for (int j = 0; j < 8; ++j) {
            const int kf = g * 8 + j;
            bf16x8 af = *(const bf16x8*)&sA[fm * SAP2 + kf * 32 + fq * 8];
            acc = __builtin_amdgcn_mfma_f32_16x16x32_bf16(af, bReg[cur][j], acc, 0, 0, 0);
        }
    }

    // C/D layout: col = lane&15 (-> n = w*16+fm), row = (lane>>4)*4 + r (-> m).
    // partial layout [kq][b][l][o] fp32.
    float* pbase = part + (((size_t)kq * 8 + b) * LDIM + m0 + fq * 4) * FDIM + w * 16 + fm;
    #pragma unroll
    for (int r = 0; r < 4; ++r)
        pbase[(size_t)r * FDIM] = acc[r];
}

// Kernel 3: out = sum_kq partial[kq] + bias.
__global__ __launch_bounds__(256) void reduce_kernel(
    const float* __restrict__ part, const float* __restrict__ bias,
    float* __restrict__ out)
{
    const size_t i = (size_t)blockIdx.x * 256 + threadIdx.x;   // float4 index
    const float4* p = (const float4*)part;
    float4 a = p[i];
    float4 c = p[i + PQ_F4];
    float4 d = p[i + 2 * (size_t)PQ_F4];
    float4 e = p[i + 3 * (size_t)PQ_F4];
    float4 bv = *(const float4*)(bias + ((i & 15) << 2));
    float4 r;
    r.x = a.x + c.x + d.x + e.x + bv.x;
    r.y = a.y + c.y + d.y + e.y + bv.y;
    r.z = a.z + c.z + d.z + e.z + bv.z;
    r.w = a.w + c.w + d.w + e.w + bv.w;
    ((float4*)out)[i] = r;
}

extern "C" void kernel_launch(void* const* d_in, const int* in_sizes, int n_in,
                              void* d_out, int out_size, void* d_ws, size_t ws_size,
                              hipStream_t stream) {
    const float* text   = (const float*)d_in[0];
    const float* adj    = (const float*)d_in[1];
    const float* weight = (const float*)d_in[2];
    const float* bias   = (const float*)d_in[3];
    float* out = (float*)d_out;
    unsigned short* hT = (unsigned short*)d_ws;                 // 4 MB
    float* part = (float*)((char*)d_ws + (8u << 20));           // 32 MB at offset 8 MB

    hidden_kernel<<<512, 256, 0, stream>>>(text, weight, hT);
    gemm_kernel<<<8192, 256, 0, stream>>>(adj, hT, part);
    reduce_kernel<<<2048, 256, 0, stream>>>(part, bias, out);
}